// Round 2
// baseline (296.746 us; speedup 1.0000x reference)
//
#include <hip/hip_runtime.h>
#include <hip/hip_bf16.h>
#include <math.h>

#define NSUB 16
#define NLAB 8
#define KG 128
#define BN 16384
#define DD 1024

typedef float v4f __attribute__((ext_vector_type(4)));
typedef short short8v __attribute__((ext_vector_type(8)));
typedef unsigned short ushort4v __attribute__((ext_vector_type(4)));

static __device__ __forceinline__ short f2bf(float f) {
    unsigned u = __builtin_bit_cast(unsigned, f);
    unsigned r = (u + 0x7fffu + ((u >> 16) & 1u)) >> 16;   // RNE
    return (short)r;
}

static __device__ __forceinline__ float bf2f(unsigned short u) {
    unsigned v = ((unsigned)u) << 16;
    return __builtin_bit_cast(float, v);
}

static __device__ __forceinline__ unsigned packbf2(float x, float y) {
    union { __hip_bfloat162 h; unsigned u; } c;
    c.h = __float22bfloat162_rn(float2{x, y});
    return c.u;
}

// K0: gid + per-block group histogram (plain stores; no global atomics, no memset)
__global__ __launch_bounds__(1024) void k0_gid(const int* __restrict__ subject,
                                               const int* __restrict__ labels,
                                               int* __restrict__ gid, int* __restrict__ hist) {
    __shared__ int h[KG];
    int t = threadIdx.x;
    if (t < KG) h[t] = 0;
    __syncthreads();
    int b = blockIdx.x * 1024 + t;
    int g = subject[b] * NLAB + labels[b];
    gid[b] = g;
    atomicAdd(&h[g], 1);
    __syncthreads();
    if (t < KG) hist[blockIdx.x * KG + t] = h[t];
}

// K0c: counting sort with deterministic block bases from hist matrix (no cursor).
__global__ __launch_bounds__(1024) void k0c_scatter(const int* __restrict__ gid,
                                                    const int* __restrict__ hist,
                                                    int* __restrict__ cnt,
                                                    int* __restrict__ rowlist) {
    __shared__ int tots[KG], base0[KG], lcur[KG];
    int t = threadIdx.x, bi = blockIdx.x;
    if (t < KG) {
        int tot = 0, pre = 0;
#pragma unroll
        for (int j = 0; j < 16; ++j) {
            int v = hist[j * KG + t];
            tot += v;
            if (j < bi) pre += v;
        }
        tots[t] = tot;
        base0[t] = pre;
        lcur[t] = 0;
        if (bi == 0) cnt[t] = tot;
    }
    __syncthreads();
    if (t < KG) {
        int o = 0;
        for (int j = 0; j < t; ++j) o += tots[j];
        base0[t] += o;
    }
    __syncthreads();
    int b = bi * 1024 + t;
    int g = gid[b];
    rowlist[base0[g] + atomicAdd(&lcur[g], 1)] = b;
}

// K1: centroid slice for (group g, d-half) -> fragment-tiled bf16 Btil + partial ||c||^2.
// ALSO emits Atil: X rounded to bf16 in MFMA-A-fragment order:
//   Atil ushort index = rt*16384 + kc*512 + q*128 + m*8 + jj
//   where feat row r = b + c*BN, rt = r>>4, m = r&15, k = kc*32 + q*8 + jj.
__global__ __launch_bounds__(256) void k1_centroid(const float* __restrict__ X,
                                                   const int* __restrict__ rowlist,
                                                   const int* __restrict__ cnt,
                                                   unsigned short* __restrict__ Btil,
                                                   float* __restrict__ cnormPart,
                                                   unsigned short* __restrict__ Atil) {
    int g = blockIdx.x >> 1;
    int half = blockIdx.x & 1;
    int t = threadIdx.x, lane = t & 63, w = t >> 6;
    int d = half * 512 + t * 2;
    int kc = d >> 5, q = (d >> 3) & 3, jj = d & 7;
    int base_t = kc * 512 + q * 128 + jj;          // (kc*64 + q*16)*8 + jj
    __shared__ int rows[512];
    __shared__ int sh_no[2];
    __shared__ float wsum[4];
    if (w == 0) {
        int v = 0;
        if (lane < g) v += cnt[lane];
        if (lane + 64 < g) v += cnt[lane + 64];
#pragma unroll
        for (int x = 32; x; x >>= 1) v += __shfl_xor(v, x, 64);
        if (lane == 0) { sh_no[0] = v; sh_no[1] = cnt[g]; }
    }
    __syncthreads();
    int o = sh_no[0], n = min(sh_no[1], 512);
    for (int i = t; i < n; i += 256) rows[i] = rowlist[o + i];
    __syncthreads();
    float ax = 0.f, ay = 0.f;
    int i = 0;
    for (; i + 16 <= n; i += 16) {
        float2 v[32];
        int rb[16];
#pragma unroll
        for (int u = 0; u < 16; ++u) {
            rb[u] = rows[i + u];
            size_t base = (size_t)rb[u] * 2048 + d;
            v[2 * u] = *(const float2*)(X + base);
            v[2 * u + 1] = *(const float2*)(X + base + 1024);
        }
#pragma unroll
        for (int u = 0; u < 16; ++u) {
            ax += v[2 * u].x + v[2 * u + 1].x;
            ay += v[2 * u].y + v[2 * u + 1].y;
            size_t rm = (size_t)(rb[u] >> 4) * 16384 + (size_t)(rb[u] & 15) * 8;
            *(unsigned*)(Atil + rm + base_t) = packbf2(v[2 * u].x, v[2 * u].y);
            *(unsigned*)(Atil + rm + 16777216 + base_t) = packbf2(v[2 * u + 1].x, v[2 * u + 1].y);
        }
    }
    for (; i < n; ++i) {
        int b = rows[i];
        size_t base = (size_t)b * 2048 + d;
        float2 v0 = *(const float2*)(X + base);
        float2 v1 = *(const float2*)(X + base + 1024);
        ax += v0.x + v1.x; ay += v0.y + v1.y;
        size_t rm = (size_t)(b >> 4) * 16384 + (size_t)(b & 15) * 8;
        *(unsigned*)(Atil + rm + base_t) = packbf2(v0.x, v0.y);
        *(unsigned*)(Atil + rm + 16777216 + base_t) = packbf2(v1.x, v1.y);
    }
    float inv = 1.f / (2.f * (float)n);
    float cx = ax * inv, cy = ay * inv;
    int gt = g >> 4, mc = g & 15;
    *(unsigned*)(Btil + (size_t)gt * 16384 + mc * 8 + base_t) = packbf2(cx, cy);
    float s = cx * cx + cy * cy;
#pragma unroll
    for (int x = 32; x; x >>= 1) s += __shfl_xor(s, x, 64);
    if (lane == 0) wsum[w] = s;
    __syncthreads();
    if (t == 0) cnormPart[half * KG + g] = wsum[0] + wsum[1] + wsum[2] + wsum[3];
}

// K5a: pure bf16 MFMA GEMM from fragment-tiled Atil/Btil. Every global load is a
// 64-lane-contiguous 1 KB burst. Depth-4 register pipeline, no packing, no fp32 loads.
// Row norms accumulated from the bf16 fragments (consistent with the bf16 dot).
// Dot stored bf16 in k5b-coalesced layout:
//   ushort idx = ((rowblk*32 + (g>>2))*64 + (row&63))*4 + (g&3)
__global__ __launch_bounds__(256) void k5a_dot(const unsigned short* __restrict__ Atil,
                                               const unsigned short* __restrict__ Btil,
                                               const int* __restrict__ gid,
                                               const float* __restrict__ cnormPart,
                                               unsigned short* __restrict__ Dotb,
                                               float* __restrict__ sqsPart) {
    __shared__ float h[KG];
    __shared__ float cnormS[KG];
    int t = threadIdx.x, lane = t & 63;
    if (t < KG) {
        h[t] = 0.f;
        cnormS[t] = cnormPart[t] + cnormPart[KG + t];
    }
    __syncthreads();
    int gw = blockIdx.x * 4 + (t >> 6);
    int row0 = gw * 32;
    int m = lane & 15, q = lane >> 4;
    const unsigned short* a0 = Atil + (size_t)(gw * 2) * 16384 + lane * 8;
    const unsigned short* a1 = a0 + 16384;
    const unsigned short* bb = Btil + lane * 8;

    v4f acc[2][8];
#pragma unroll
    for (int i = 0; i < 2; ++i)
#pragma unroll
        for (int j = 0; j < 8; ++j) acc[i][j] = (v4f){0.f, 0.f, 0.f, 0.f};

    short8v A0[4], A1[4], Bf[4][8];
#pragma unroll
    for (int p = 0; p < 4; ++p) {
        A0[p] = *(const short8v*)(a0 + p * 512);
        A1[p] = *(const short8v*)(a1 + p * 512);
#pragma unroll
        for (int gt = 0; gt < 8; ++gt)
            Bf[p][gt] = *(const short8v*)(bb + (size_t)gt * 16384 + p * 512);
    }
    float s0 = 0.f, s1 = 0.f;
#pragma unroll
    for (int kc = 0; kc < 32; ++kc) {
        const int cur = kc & 3;
        short8v nA0, nA1, nB[8];
        if (kc + 4 < 32) {
            nA0 = *(const short8v*)(a0 + (kc + 4) * 512);
            nA1 = *(const short8v*)(a1 + (kc + 4) * 512);
#pragma unroll
            for (int gt = 0; gt < 8; ++gt)
                nB[gt] = *(const short8v*)(bb + (size_t)gt * 16384 + (kc + 4) * 512);
        }
#pragma unroll
        for (int gt = 0; gt < 8; ++gt) {
            acc[0][gt] = __builtin_amdgcn_mfma_f32_16x16x32_bf16(A0[cur], Bf[cur][gt], acc[0][gt], 0, 0, 0);
            acc[1][gt] = __builtin_amdgcn_mfma_f32_16x16x32_bf16(A1[cur], Bf[cur][gt], acc[1][gt], 0, 0, 0);
        }
        {
            union { short8v s; unsigned u[4]; } ua, ub;
            ua.s = A0[cur]; ub.s = A1[cur];
#pragma unroll
            for (int r = 0; r < 4; ++r) {
                float l0 = __builtin_bit_cast(float, ua.u[r] << 16);
                float h0 = __builtin_bit_cast(float, ua.u[r] & 0xffff0000u);
                s0 = fmaf(l0, l0, s0); s0 = fmaf(h0, h0, s0);
                float l1 = __builtin_bit_cast(float, ub.u[r] << 16);
                float h1 = __builtin_bit_cast(float, ub.u[r] & 0xffff0000u);
                s1 = fmaf(l1, l1, s1); s1 = fmaf(h1, h1, s1);
            }
        }
        if (kc + 4 < 32) {
            A0[cur] = nA0; A1[cur] = nA1;
#pragma unroll
            for (int gt = 0; gt < 8; ++gt) Bf[cur][gt] = nB[gt];
        }
    }

    // s0 = ||row0+(lane&15)||^2, s1 = ||row0+16+(lane&15)||^2 on all lanes
    s0 += __shfl_xor(s0, 16, 64); s0 += __shfl_xor(s0, 32, 64);
    s1 += __shfl_xor(s1, 16, 64); s1 += __shfl_xor(s1, 32, 64);

    int rowblk = row0 >> 6, rlo = row0 & 32;
#pragma unroll
    for (int tile = 0; tile < 2; ++tile)
#pragma unroll
        for (int reg = 0; reg < 4; ++reg) {
            int rr = rlo + tile * 16 + q * 4 + reg;
            int row = (rowblk << 6) + rr;
            int b = row & (BN - 1);
            int g = gid[b];
            float own = 0.f;
#pragma unroll
            for (int gt = 0; gt < 8; ++gt) {
                float v = acc[tile][gt][reg];
                size_t idx = (((size_t)rowblk * 32 + gt * 4 + (m >> 2)) * 64 + rr) * 4 + (m & 3);
                Dotb[idx] = (unsigned short)f2bf(v);
                if ((g >> 4) == gt) own = v;
            }
            float rn = __shfl(tile ? s1 : s0, q * 4 + reg, 64);
            if ((g & 15) == m) {
                float d2 = fmaxf(rn - 2.f * own + cnormS[g], 0.f);
                atomicAdd(&h[g], sqrtf(sqrtf(d2)));   // sqrt(dist), dist = sqrt(d2)
            }
        }
    __syncthreads();
    if (t < KG) sqsPart[(size_t)blockIdx.x * KG + t] = h[t];
}

// K5b: density post-processing + loss. 256 blocks x 128 threads (all threads active in
// density phase). Dot read as contiguous 8 B/lane ushort4 pairs from the tiled layout;
// chunk pair (2c, 2c+1) holds subject c's 8 labels (same structure as before).
__global__ __launch_bounds__(128) void k5b_loss(const unsigned short* __restrict__ Dotb,
                                                const int* __restrict__ gid,
                                                const float* __restrict__ sqsPart,
                                                const int* __restrict__ cnt,
                                                float* __restrict__ out) {
    __shared__ float tmp[KG], d1s[KG], qv[4];
    __shared__ float recipDen[KG];
    __shared__ float wsum[2];
    int t = threadIdx.x;
    // ---- density (all 128 threads; barriers uniform) ----
    float cntf = 0.f, d0v = 0.f, v = 0.f;
    if (t < KG) {
        float ss = 0.f;
        for (int j = 0; j < 256; j += 4)
            ss += sqsPart[(size_t)j * KG + t] + sqsPart[(size_t)(j + 1) * KG + t] +
                  sqsPart[(size_t)(j + 2) * KG + t] + sqsPart[(size_t)(j + 3) * KG + t];
        cntf = 2.f * (float)cnt[t];
        d0v = (ss / cntf) / logf(cntf + 10.f);
        tmp[t] = d0v;
    }
    __syncthreads();
    if (t < KG) {
        float dmax = -INFINITY;
        for (int j = 0; j < KG; ++j) dmax = fmaxf(dmax, tmp[j]);
        v = (cntf <= 1.f) ? dmax : d0v;
        d1s[t] = v;
    }
    __syncthreads();
    if (t < KG) {
        int less = 0, eq = 0;
        for (int j = 0; j < KG; ++j) {
            float u = d1s[j];
            less += (u < v) ? 1 : 0;
            eq += (u == v) ? 1 : 0;
        }
        // quantile(0.1): idx 12.7 -> 0.3*v[12]+0.7*v[13]; quantile(0.9): 0.7*v[114]+0.3*v[115]
        const int ppos[4] = {12, 13, 114, 115};
        for (int qq = 0; qq < 4; ++qq)
            if (less <= ppos[qq] && ppos[qq] < less + eq) qv[qq] = v;
    }
    __syncthreads();
    if (t < KG) {
        float q10 = 0.3f * qv[0] + 0.7f * qv[1];
        float q90 = 0.7f * qv[2] + 0.3f * qv[3];
        tmp[t] = fminf(fmaxf(v, q10), q90);
    }
    __syncthreads();
    if (t < KG) {
        float sum = 0.f;
        for (int j = 0; j < KG; ++j) sum += tmp[j];
        float mean = sum / (float)KG;
        recipDen[t] = mean / (0.1f * tmp[t]);   // 1/den
    }
    __syncthreads();
    // ---- loss: one thread per row ----
    int row = blockIdx.x * 128 + t;
    int b = row & (BN - 1);
    int g = gid[b];
    int s = g >> 3, l = g & 7;
    int lane = t & 63, w = t >> 6;
    size_t rowblk = (size_t)(row >> 6);
    const ushort4v* dp = (const ushort4v*)Dotb;
    float mx = -INFINITY;
    float psave[16];
#pragma unroll
    for (int c = 0; c < 16; ++c) {
        size_t i0 = (rowblk * 32 + c * 2) * 64 + lane;
        ushort4v dv0 = dp[i0];
        ushort4v dv1 = dp[i0 + 64];
        const float* rv = &recipDen[c * 8];
        float x[8];
#pragma unroll
        for (int j = 0; j < 4; ++j) x[j] = bf2f((unsigned short)dv0[j]) * rv[j];
#pragma unroll
        for (int j = 0; j < 4; ++j) x[4 + j] = bf2f((unsigned short)dv1[j]) * rv[4 + j];
#pragma unroll
        for (int j = 0; j < 8; ++j) mx = fmaxf(mx, x[j]);
        float sel = x[0];
#pragma unroll
        for (int j = 1; j < 8; ++j) sel = (j == l) ? x[j] : sel;
        psave[c] = sel;
    }
    float S = 0.f, P = 0.f;
#pragma unroll
    for (int j = 0; j < 16; ++j) {
        float pv = psave[j] - mx;
        float e = expf(pv);
        bool use = (j != s);
        S += use ? e : 0.f;
        P += use ? pv : 0.f;
    }
    // 113 masked-out entries contribute exp(0)=1 each to the softmax denominator
    float ll = logf(113.f + S) - P * (1.f / 15.f);
#pragma unroll
    for (int x2 = 32; x2; x2 >>= 1) ll += __shfl_xor(ll, x2, 64);
    if (lane == 0) wsum[w] = ll;
    __syncthreads();
    if (t == 0) atomicAdd(out, (wsum[0] + wsum[1]) * (1.f / 32768.f));
}

extern "C" void kernel_launch(void* const* d_in, const int* in_sizes, int n_in,
                              void* d_out, int out_size, void* d_ws, size_t ws_size,
                              hipStream_t stream) {
    const float* X = (const float*)d_in[0];
    const int* subject = (const int*)d_in[1];
    const int* labels = (const int*)d_in[2];
    float* out = (float*)d_out;
    char* w = (char*)d_ws;
    int* gid = (int*)(w + 0);                              // 64 KB
    int* hist = (int*)(w + 65536);                         // 8 KB  (16 x 128)
    int* cnt = (int*)(w + 73728);                          // 512 B
    float* cnormPart = (float*)(w + 74240);                // 1 KB  (2 x 128)
    int* rowlist = (int*)(w + 131072);                     // 64 KB
    float* sqsPart = (float*)(w + 262144);                 // 128 KB (256 x 128)
    unsigned short* Btil = (unsigned short*)(w + 524288);  // 256 KB (frag-tiled centroids)
    unsigned short* Atil = (unsigned short*)(w + 2097152); // 64 MB  (frag-tiled bf16 X)
    unsigned short* Dotb = (unsigned short*)(w + 100663296); // 8 MB (tiled bf16 Dot)

    (void)hipMemsetAsync(out, 0, sizeof(float), stream);

    k0_gid<<<16, 1024, 0, stream>>>(subject, labels, gid, hist);
    k0c_scatter<<<16, 1024, 0, stream>>>(gid, hist, cnt, rowlist);
    k1_centroid<<<KG * 2, 256, 0, stream>>>(X, rowlist, cnt, Btil, cnormPart, Atil);
    k5a_dot<<<256, 256, 0, stream>>>(Atil, Btil, gid, cnormPart, Dotb, sqsPart);
    k5b_loss<<<256, 128, 0, stream>>>(Dotb, gid, sqsPart, cnt, out);
}

// Round 3
// 261.297 us; speedup vs baseline: 1.1357x; 1.1357x over previous
//
#include <hip/hip_runtime.h>
#include <hip/hip_bf16.h>
#include <math.h>

#define NSUB 16
#define NLAB 8
#define KG 128
#define BN 16384
#define DD 1024

typedef float v4f __attribute__((ext_vector_type(4)));
typedef short short8v __attribute__((ext_vector_type(8)));
typedef unsigned short ushort4v __attribute__((ext_vector_type(4)));

static __device__ __forceinline__ short f2bf(float f) {
    unsigned u = __builtin_bit_cast(unsigned, f);
    unsigned r = (u + 0x7fffu + ((u >> 16) & 1u)) >> 16;   // RNE
    return (short)r;
}

static __device__ __forceinline__ float bf2f(unsigned short u) {
    unsigned v = ((unsigned)u) << 16;
    return __builtin_bit_cast(float, v);
}

static __device__ __forceinline__ unsigned packbf2(float x, float y) {
    union { __hip_bfloat162 h; unsigned u; } c;
    c.h = __float22bfloat162_rn(float2{x, y});
    return c.u;
}

// K0: gid + per-block group histogram (plain stores; no global atomics, no memset)
__global__ __launch_bounds__(1024) void k0_gid(const int* __restrict__ subject,
                                               const int* __restrict__ labels,
                                               int* __restrict__ gid, int* __restrict__ hist) {
    __shared__ int h[KG];
    int t = threadIdx.x;
    if (t < KG) h[t] = 0;
    __syncthreads();
    int b = blockIdx.x * 1024 + t;
    int g = subject[b] * NLAB + labels[b];
    gid[b] = g;
    atomicAdd(&h[g], 1);
    __syncthreads();
    if (t < KG) hist[blockIdx.x * KG + t] = h[t];
}

// K0c: counting sort with deterministic block bases from hist matrix (no cursor).
__global__ __launch_bounds__(1024) void k0c_scatter(const int* __restrict__ gid,
                                                    const int* __restrict__ hist,
                                                    int* __restrict__ cnt,
                                                    int* __restrict__ rowlist) {
    __shared__ int tots[KG], base0[KG], lcur[KG];
    int t = threadIdx.x, bi = blockIdx.x;
    if (t < KG) {
        int tot = 0, pre = 0;
#pragma unroll
        for (int j = 0; j < 16; ++j) {
            int v = hist[j * KG + t];
            tot += v;
            if (j < bi) pre += v;
        }
        tots[t] = tot;
        base0[t] = pre;
        lcur[t] = 0;
        if (bi == 0) cnt[t] = tot;
    }
    __syncthreads();
    if (t < KG) {
        int o = 0;
        for (int j = 0; j < t; ++j) o += tots[j];
        base0[t] += o;
    }
    __syncthreads();
    int b = bi * 1024 + t;
    int g = gid[b];
    rowlist[base0[g] + atomicAdd(&lcur[g], 1)] = b;
}

// K1: centroid slice for (group g, d-half) -> fragment-tiled bf16 Btil + partial ||c||^2.
// (centroid-only: the scattered Atil emission was moved to k2_tile — it caused 2.3x
//  write amplification / 118 us here)
__global__ __launch_bounds__(256) void k1_centroid(const float* __restrict__ X,
                                                   const int* __restrict__ rowlist,
                                                   const int* __restrict__ cnt,
                                                   unsigned short* __restrict__ Btil,
                                                   float* __restrict__ cnormPart) {
    int g = blockIdx.x >> 1;
    int half = blockIdx.x & 1;
    int t = threadIdx.x, lane = t & 63, w = t >> 6;
    int d = half * 512 + t * 2;
    int kc = d >> 5, q = (d >> 3) & 3, jj = d & 7;
    int base_t = kc * 512 + q * 128 + jj;          // (kc*64 + q*16)*8 + jj
    __shared__ int rows[512];
    __shared__ int sh_no[2];
    __shared__ float wsum[4];
    if (w == 0) {
        int v = 0;
        if (lane < g) v += cnt[lane];
        if (lane + 64 < g) v += cnt[lane + 64];
#pragma unroll
        for (int x = 32; x; x >>= 1) v += __shfl_xor(v, x, 64);
        if (lane == 0) { sh_no[0] = v; sh_no[1] = cnt[g]; }
    }
    __syncthreads();
    int o = sh_no[0], n = min(sh_no[1], 512);
    for (int i = t; i < n; i += 256) rows[i] = rowlist[o + i];
    __syncthreads();
    float ax = 0.f, ay = 0.f;
    int i = 0;
    for (; i + 16 <= n; i += 16) {
        float2 v[32];
#pragma unroll
        for (int u = 0; u < 16; ++u) {
            size_t base = (size_t)rows[i + u] * 2048 + d;
            v[2 * u] = *(const float2*)(X + base);
            v[2 * u + 1] = *(const float2*)(X + base + 1024);
        }
#pragma unroll
        for (int u = 0; u < 32; ++u) { ax += v[u].x; ay += v[u].y; }
    }
    for (; i < n; ++i) {
        size_t base = (size_t)rows[i] * 2048 + d;
        float2 v0 = *(const float2*)(X + base);
        float2 v1 = *(const float2*)(X + base + 1024);
        ax += v0.x + v1.x; ay += v0.y + v1.y;
    }
    float inv = 1.f / (2.f * (float)n);
    float cx = ax * inv, cy = ay * inv;
    int gt = g >> 4, mc = g & 15;
    *(unsigned*)(Btil + (size_t)gt * 16384 + mc * 8 + base_t) = packbf2(cx, cy);
    float s = cx * cx + cy * cy;
#pragma unroll
    for (int x = 32; x; x >>= 1) s += __shfl_xor(s, x, 64);
    if (lane == 0) wsum[w] = s;
    __syncthreads();
    if (t == 0) cnormPart[half * KG + g] = wsum[0] + wsum[1] + wsum[2] + wsum[3];
}

// K2: X (row-major fp32) -> Atil (frag-tiled bf16), both sides fully coalesced.
// One block per 16-row tile rt: feat rows rt*16+m (all same c, consecutive b).
// LDS row-major with XOR swizzle: word idx = m*512 + ((d>>1) ^ ((m&7)<<2)).
// Store side: contiguous (conflict-free). Read side: b128, uniform 8-deep (minimum).
// Atil ushort index = rt*16384 + kc*512 + q*128 + m*8 + jj, k = kc*32 + q*8 + jj.
__global__ __launch_bounds__(256) void k2_tile(const float* __restrict__ X,
                                               unsigned short* __restrict__ Atil) {
    __shared__ unsigned lds[8192];   // 32 KB
    int t = threadIdx.x, lane = t & 63, w = t >> 6;
    int rt = blockIdx.x;
#pragma unroll
    for (int p = 0; p < 4; ++p) {
        int m = w * 4 + p;
        int r = rt * 16 + m;
        const float* xp = X + (size_t)(r & (BN - 1)) * 2048 + (size_t)(r >> 14) * 1024;
        unsigned swz = (unsigned)((m & 7) << 2);
        unsigned mbase = (unsigned)m * 512;
#pragma unroll
        for (int j = 0; j < 4; ++j) {
            int d0 = j * 256 + lane * 4;
            float4 v = *(const float4*)(xp + d0);
            unsigned wi = mbase + (((unsigned)(d0 >> 1)) ^ swz);
            lds[wi] = packbf2(v.x, v.y);
            lds[wi + 1] = packbf2(v.z, v.w);
        }
    }
    __syncthreads();
    size_t gbase = (size_t)rt * 16384;
#pragma unroll
    for (int p = 0; p < 8; ++p) {
        int wo = p * 1024 + t * 4;              // u32 index into the tile (16B per thread)
        int kc = wo >> 8;
        int q = (wo >> 6) & 3;
        int m = (wo >> 2) & 15;
        unsigned wi = (unsigned)m * 512 +
                      (((unsigned)(kc * 16 + q * 4)) ^ (unsigned)((m & 7) << 2));
        uint4 val = *(const uint4*)&lds[wi];
        *(uint4*)(Atil + gbase + (size_t)wo * 2) = val;
    }
}

// K5a: pure bf16 MFMA GEMM from fragment-tiled Atil/Btil. Every global load is a
// 64-lane-contiguous 1 KB burst. Depth-4 register pipeline, no packing, no fp32 loads.
// Row norms accumulated from the bf16 fragments (consistent with the bf16 dot).
// Dot stored bf16 in k5b-coalesced layout:
//   ushort idx = ((rowblk*32 + (g>>2))*64 + (row&63))*4 + (g&3)
__global__ __launch_bounds__(256) void k5a_dot(const unsigned short* __restrict__ Atil,
                                               const unsigned short* __restrict__ Btil,
                                               const int* __restrict__ gid,
                                               const float* __restrict__ cnormPart,
                                               unsigned short* __restrict__ Dotb,
                                               float* __restrict__ sqsPart) {
    __shared__ float h[KG];
    __shared__ float cnormS[KG];
    int t = threadIdx.x, lane = t & 63;
    if (t < KG) {
        h[t] = 0.f;
        cnormS[t] = cnormPart[t] + cnormPart[KG + t];
    }
    __syncthreads();
    int gw = blockIdx.x * 4 + (t >> 6);
    int row0 = gw * 32;
    int m = lane & 15, q = lane >> 4;
    const unsigned short* a0 = Atil + (size_t)(gw * 2) * 16384 + lane * 8;
    const unsigned short* a1 = a0 + 16384;
    const unsigned short* bb = Btil + lane * 8;

    v4f acc[2][8];
#pragma unroll
    for (int i = 0; i < 2; ++i)
#pragma unroll
        for (int j = 0; j < 8; ++j) acc[i][j] = (v4f){0.f, 0.f, 0.f, 0.f};

    short8v A0[4], A1[4], Bf[4][8];
#pragma unroll
    for (int p = 0; p < 4; ++p) {
        A0[p] = *(const short8v*)(a0 + p * 512);
        A1[p] = *(const short8v*)(a1 + p * 512);
#pragma unroll
        for (int gt = 0; gt < 8; ++gt)
            Bf[p][gt] = *(const short8v*)(bb + (size_t)gt * 16384 + p * 512);
    }
    float s0 = 0.f, s1 = 0.f;
#pragma unroll
    for (int kc = 0; kc < 32; ++kc) {
        const int cur = kc & 3;
        short8v nA0, nA1, nB[8];
        if (kc + 4 < 32) {
            nA0 = *(const short8v*)(a0 + (kc + 4) * 512);
            nA1 = *(const short8v*)(a1 + (kc + 4) * 512);
#pragma unroll
            for (int gt = 0; gt < 8; ++gt)
                nB[gt] = *(const short8v*)(bb + (size_t)gt * 16384 + (kc + 4) * 512);
        }
#pragma unroll
        for (int gt = 0; gt < 8; ++gt) {
            acc[0][gt] = __builtin_amdgcn_mfma_f32_16x16x32_bf16(A0[cur], Bf[cur][gt], acc[0][gt], 0, 0, 0);
            acc[1][gt] = __builtin_amdgcn_mfma_f32_16x16x32_bf16(A1[cur], Bf[cur][gt], acc[1][gt], 0, 0, 0);
        }
        {
            union { short8v s; unsigned u[4]; } ua, ub;
            ua.s = A0[cur]; ub.s = A1[cur];
#pragma unroll
            for (int r = 0; r < 4; ++r) {
                float l0 = __builtin_bit_cast(float, ua.u[r] << 16);
                float h0 = __builtin_bit_cast(float, ua.u[r] & 0xffff0000u);
                s0 = fmaf(l0, l0, s0); s0 = fmaf(h0, h0, s0);
                float l1 = __builtin_bit_cast(float, ub.u[r] << 16);
                float h1 = __builtin_bit_cast(float, ub.u[r] & 0xffff0000u);
                s1 = fmaf(l1, l1, s1); s1 = fmaf(h1, h1, s1);
            }
        }
        if (kc + 4 < 32) {
            A0[cur] = nA0; A1[cur] = nA1;
#pragma unroll
            for (int gt = 0; gt < 8; ++gt) Bf[cur][gt] = nB[gt];
        }
    }

    // s0 = ||row0+(lane&15)||^2, s1 = ||row0+16+(lane&15)||^2 on all lanes
    s0 += __shfl_xor(s0, 16, 64); s0 += __shfl_xor(s0, 32, 64);
    s1 += __shfl_xor(s1, 16, 64); s1 += __shfl_xor(s1, 32, 64);

    int rowblk = row0 >> 6, rlo = row0 & 32;
#pragma unroll
    for (int tile = 0; tile < 2; ++tile)
#pragma unroll
        for (int reg = 0; reg < 4; ++reg) {
            int rr = rlo + tile * 16 + q * 4 + reg;
            int row = (rowblk << 6) + rr;
            int b = row & (BN - 1);
            int g = gid[b];
            float own = 0.f;
#pragma unroll
            for (int gt = 0; gt < 8; ++gt) {
                float v = acc[tile][gt][reg];
                size_t idx = (((size_t)rowblk * 32 + gt * 4 + (m >> 2)) * 64 + rr) * 4 + (m & 3);
                Dotb[idx] = (unsigned short)f2bf(v);
                if ((g >> 4) == gt) own = v;
            }
            float rn = __shfl(tile ? s1 : s0, q * 4 + reg, 64);
            if ((g & 15) == m) {
                float d2 = fmaxf(rn - 2.f * own + cnormS[g], 0.f);
                atomicAdd(&h[g], sqrtf(sqrtf(d2)));   // sqrt(dist), dist = sqrt(d2)
            }
        }
    __syncthreads();
    if (t < KG) sqsPart[(size_t)blockIdx.x * KG + t] = h[t];
}

// K5b: density post-processing + loss. 256 blocks x 128 threads (all threads active in
// density phase). Dot read as contiguous 8 B/lane ushort4 pairs from the tiled layout;
// chunk pair (2c, 2c+1) holds subject c's 8 labels (same structure as before).
__global__ __launch_bounds__(128) void k5b_loss(const unsigned short* __restrict__ Dotb,
                                                const int* __restrict__ gid,
                                                const float* __restrict__ sqsPart,
                                                const int* __restrict__ cnt,
                                                float* __restrict__ out) {
    __shared__ float tmp[KG], d1s[KG], qv[4];
    __shared__ float recipDen[KG];
    __shared__ float wsum[2];
    int t = threadIdx.x;
    // ---- density (all 128 threads; barriers uniform) ----
    float cntf = 0.f, d0v = 0.f, v = 0.f;
    if (t < KG) {
        float ss = 0.f;
        for (int j = 0; j < 256; j += 4)
            ss += sqsPart[(size_t)j * KG + t] + sqsPart[(size_t)(j + 1) * KG + t] +
                  sqsPart[(size_t)(j + 2) * KG + t] + sqsPart[(size_t)(j + 3) * KG + t];
        cntf = 2.f * (float)cnt[t];
        d0v = (ss / cntf) / logf(cntf + 10.f);
        tmp[t] = d0v;
    }
    __syncthreads();
    if (t < KG) {
        float dmax = -INFINITY;
        for (int j = 0; j < KG; ++j) dmax = fmaxf(dmax, tmp[j]);
        v = (cntf <= 1.f) ? dmax : d0v;
        d1s[t] = v;
    }
    __syncthreads();
    if (t < KG) {
        int less = 0, eq = 0;
        for (int j = 0; j < KG; ++j) {
            float u = d1s[j];
            less += (u < v) ? 1 : 0;
            eq += (u == v) ? 1 : 0;
        }
        // quantile(0.1): idx 12.7 -> 0.3*v[12]+0.7*v[13]; quantile(0.9): 0.7*v[114]+0.3*v[115]
        const int ppos[4] = {12, 13, 114, 115};
        for (int qq = 0; qq < 4; ++qq)
            if (less <= ppos[qq] && ppos[qq] < less + eq) qv[qq] = v;
    }
    __syncthreads();
    if (t < KG) {
        float q10 = 0.3f * qv[0] + 0.7f * qv[1];
        float q90 = 0.7f * qv[2] + 0.3f * qv[3];
        tmp[t] = fminf(fmaxf(v, q10), q90);
    }
    __syncthreads();
    if (t < KG) {
        float sum = 0.f;
        for (int j = 0; j < KG; ++j) sum += tmp[j];
        float mean = sum / (float)KG;
        recipDen[t] = mean / (0.1f * tmp[t]);   // 1/den
    }
    __syncthreads();
    // ---- loss: one thread per row ----
    int row = blockIdx.x * 128 + t;
    int b = row & (BN - 1);
    int g = gid[b];
    int s = g >> 3, l = g & 7;
    int lane = t & 63, w = t >> 6;
    size_t rowblk = (size_t)(row >> 6);
    const ushort4v* dp = (const ushort4v*)Dotb;
    float mx = -INFINITY;
    float psave[16];
#pragma unroll
    for (int c = 0; c < 16; ++c) {
        size_t i0 = (rowblk * 32 + c * 2) * 64 + lane;
        ushort4v dv0 = dp[i0];
        ushort4v dv1 = dp[i0 + 64];
        const float* rv = &recipDen[c * 8];
        float x[8];
#pragma unroll
        for (int j = 0; j < 4; ++j) x[j] = bf2f((unsigned short)dv0[j]) * rv[j];
#pragma unroll
        for (int j = 0; j < 4; ++j) x[4 + j] = bf2f((unsigned short)dv1[j]) * rv[4 + j];
#pragma unroll
        for (int j = 0; j < 8; ++j) mx = fmaxf(mx, x[j]);
        float sel = x[0];
#pragma unroll
        for (int j = 1; j < 8; ++j) sel = (j == l) ? x[j] : sel;
        psave[c] = sel;
    }
    float S = 0.f, P = 0.f;
#pragma unroll
    for (int j = 0; j < 16; ++j) {
        float pv = psave[j] - mx;
        float e = expf(pv);
        bool use = (j != s);
        S += use ? e : 0.f;
        P += use ? pv : 0.f;
    }
    // 113 masked-out entries contribute exp(0)=1 each to the softmax denominator
    float ll = logf(113.f + S) - P * (1.f / 15.f);
#pragma unroll
    for (int x2 = 32; x2; x2 >>= 1) ll += __shfl_xor(ll, x2, 64);
    if (lane == 0) wsum[w] = ll;
    __syncthreads();
    if (t == 0) atomicAdd(out, (wsum[0] + wsum[1]) * (1.f / 32768.f));
}

extern "C" void kernel_launch(void* const* d_in, const int* in_sizes, int n_in,
                              void* d_out, int out_size, void* d_ws, size_t ws_size,
                              hipStream_t stream) {
    const float* X = (const float*)d_in[0];
    const int* subject = (const int*)d_in[1];
    const int* labels = (const int*)d_in[2];
    float* out = (float*)d_out;
    char* w = (char*)d_ws;
    int* gid = (int*)(w + 0);                              // 64 KB
    int* hist = (int*)(w + 65536);                         // 8 KB  (16 x 128)
    int* cnt = (int*)(w + 73728);                          // 512 B
    float* cnormPart = (float*)(w + 74240);                // 1 KB  (2 x 128)
    int* rowlist = (int*)(w + 131072);                     // 64 KB
    float* sqsPart = (float*)(w + 262144);                 // 128 KB (256 x 128)
    unsigned short* Btil = (unsigned short*)(w + 524288);  // 256 KB (frag-tiled centroids)
    unsigned short* Atil = (unsigned short*)(w + 2097152); // 64 MB  (frag-tiled bf16 X)
    unsigned short* Dotb = (unsigned short*)(w + 100663296); // 8 MB (tiled bf16 Dot)

    (void)hipMemsetAsync(out, 0, sizeof(float), stream);

    k0_gid<<<16, 1024, 0, stream>>>(subject, labels, gid, hist);
    k0c_scatter<<<16, 1024, 0, stream>>>(gid, hist, cnt, rowlist);
    k1_centroid<<<KG * 2, 256, 0, stream>>>(X, rowlist, cnt, Btil, cnormPart);
    k2_tile<<<2048, 256, 0, stream>>>(X, Atil);
    k5a_dot<<<256, 256, 0, stream>>>(Atil, Btil, gid, cnormPart, Dotb, sqsPart);
    k5b_loss<<<256, 128, 0, stream>>>(Dotb, gid, sqsPart, cnt, out);
}